// Round 22
// baseline (480.283 us; speedup 1.0000x reference)
//
#include <hip/hip_runtime.h>
#include <stdint.h>
#include <stddef.h>

// ================= helpers =================
__device__ __forceinline__ float bl(unsigned u){ return __uint_as_float(u << 16); }
__device__ __forceinline__ float bh(unsigned u){ return __uint_as_float(u & 0xffff0000u); }
__device__ __forceinline__ unsigned short f2bf(float f){
    unsigned u = __float_as_uint(f);
    unsigned r = (u + 0x7fffu + ((u >> 16) & 1u)) >> 16;
    return (unsigned short)r;
}
// 15-bit float (5 exp bias 15, 10 mant): exp(s) for s in [-10,10] fits exactly.
__device__ __forceinline__ float dec15(unsigned e15){
    return __uint_as_float((e15 + (112u << 10)) << 13);
}
__device__ __forceinline__ float get_mask(const void* p, unsigned flags, int i){
    if((flags & 1u) == 0) return ((const int*)p)[i] ? 1.0f : 0.0f;
    if(flags & 2u)        return ((const float*)p)[i];
    return ((const unsigned char*)p)[i] ? 1.0f : 0.0f;
}

// ====== PREP: block 0 = small weight products; blocks 1.. = detection + deg zero ======
__global__ __launch_bounds__(256) void prep_kernel(
    const float* __restrict__ W0, const float* __restrict__ b0,
    const float* __restrict__ W1, const float* __restrict__ b1,
    const float* __restrict__ Wcls, const float* __restrict__ bcls,
    float* __restrict__ W0c, float* __restrict__ W1c,
    float* __restrict__ b0c, float* __restrict__ b1c,
    const unsigned char* __restrict__ mp, int n,
    const unsigned* __restrict__ li, long li_n, unsigned* __restrict__ flags,
    int* __restrict__ deg, int n3)
{
    int t = threadIdx.x;
    if(blockIdx.x == 0){
        for(int i = t; i < 2048; i += 256){
            int d = i >> 4, c = i & 15;
            float s0 = 0.f, s1 = 0.f;
            for(int k = 0; k < 64; k++){
                float wc = Wcls[k*16 + c];
                s0 += W0[d*64 + k]*wc;
                s1 += W1[d*64 + k]*wc;
            }
            W0c[i] = s0; W1c[i] = s1;
        }
        if(t < 16){
            float s0 = 0.f, s1 = 0.f;
            for(int k = 0; k < 64; k++){
                float wc = Wcls[k*16 + t];
                s0 += b0[k]*wc; s1 += b1[k]*wc;
            }
            b0c[t] = s0 + bcls[t];
            b1c[t] = s1;
        }
    } else {
        long i = (long)(blockIdx.x - 1)*256 + t;
        if(i < n3) deg[i] = 0;
        unsigned f = 0;
        if(i < n){
            unsigned char b = mp[i];
            if((i & 3) && b) f |= 1u;
            if(b == 0x3Fu)   f |= 2u;
        }
        if(i < li_n){
            if(li[i] != li[0]) f |= 4u;
        }
        if(f) atomicOr(flags, f);
    }
}

// ====== MEGA v4: grid-partitioned {count (fire&forget) | proj_fused0 | proj16} ======
// Count is FIRE-AND-FORGET (no return read) — no wave stall on the cross-XCD
// atomic round trip; the rank/cursor position is assigned later inside the
// gather-heavy scatter where its latency hides. 16 KB LDS keeps occupancy high.
__global__ __launch_bounds__(256) void mega_kernel(
    // count part
    const int* __restrict__ dst0, const int* __restrict__ dst1, const int* __restrict__ dst2,
    int* __restrict__ deg, int n, int eg, int nbCount,
    // proj_fused0 part (32-row tiles)
    const float* __restrict__ X0, const float* __restrict__ Wp,
    const float* __restrict__ W0c, const float* __restrict__ b0c,
    unsigned short* __restrict__ fph, float* __restrict__ h0c, int rows0, int nbP0,
    // proj16 part (32-row tiles)
    const float* __restrict__ X1, const float* __restrict__ W1c,
    const float* __restrict__ b1c, unsigned short* __restrict__ h1c, int rows1)
{
    __shared__ __align__(16) float ftile[4096];   // 16 KB
    int t = threadIdx.x;
    int b = blockIdx.x;
    if(b < nbCount){
        // ---- degree count, fire-and-forget ----
        long tid = (long)b*256 + t;
        if(tid < 3L*eg){
            int g = (int)(tid / eg);
            int e = (int)(tid - (long)g*eg);
            const int* dp = g==0 ? dst0 : (g==1 ? dst1 : dst2);
            atomicAdd(&deg[(long)g*n + dp[e]], 1);
        }
    } else if(b < nbCount + nbP0){
        // ---- proj_fused0: one 32-row tile; weights from global ----
        int c4 = (t & 15)*4;
        int col16 = t & 15;
        int r2 = (t >> 4)*2;
        float bc = b0c[col16];
        long base = (long)(b - nbCount)*32;
        if(base < rows0){
            int nr = min(32, (int)(rows0 - base));
            for(int i = t; i < nr*32; i += 256){
                int r = i >> 5, q = i & 31;
                ((float4*)ftile)[r*32 + q] = ((const float4*)X0)[(base + r)*32 + q];
            }
            __syncthreads();
            float a00=0,a01=0,a02=0,a03=0, a10=0,a11=0,a12=0,a13=0;
            float c0 = bc, c1 = bc;
            #pragma unroll 4
            for(int k = 0; k < 128; k++){
                float4 w = *((const float4*)(Wp + k*64 + c4));
                float wc = W0c[k*16 + col16];
                float x0 = ftile[r2*128 + k];
                float x1 = ftile[(r2+1)*128 + k];
                a00 += x0*w.x; a01 += x0*w.y; a02 += x0*w.z; a03 += x0*w.w; c0 += x0*wc;
                a10 += x1*w.x; a11 += x1*w.y; a12 += x1*w.z; a13 += x1*w.w; c1 += x1*wc;
            }
            if(r2 < nr){
                ushort4 o; o.x=f2bf(a00); o.y=f2bf(a01); o.z=f2bf(a02); o.w=f2bf(a03);
                *((ushort4*)(fph + (base + r2)*64 + c4)) = o;
                h0c[(base + r2)*16 + col16] = c0;
            }
            if(r2 + 1 < nr){
                ushort4 o; o.x=f2bf(a10); o.y=f2bf(a11); o.z=f2bf(a12); o.w=f2bf(a13);
                *((ushort4*)(fph + (base + r2 + 1)*64 + c4)) = o;
                h0c[(base + r2 + 1)*16 + col16] = c1;
            }
        }
    } else {
        // ---- proj16: one 32-row tile; W1c from global ----
        int col = t & 15;
        int r2 = (t >> 4)*2;
        float bc = b1c[col];
        long base = (long)(b - nbCount - nbP0)*32;
        if(base < rows1){
            int nr = min(32, (int)(rows1 - base));
            for(int i = t; i < nr*32; i += 256){
                int r = i >> 5, q = i & 31;
                ((float4*)ftile)[r*32 + q] = ((const float4*)X1)[(base + r)*32 + q];
            }
            __syncthreads();
            float acc0 = bc, acc1 = bc;
            #pragma unroll 4
            for(int k = 0; k < 128; k++){
                float wc = W1c[k*16 + col];
                acc0 += ftile[(r2+0)*128 + k]*wc;
                acc1 += ftile[(r2+1)*128 + k]*wc;
            }
            if(r2+0 < nr) h1c[(base + r2 + 0)*16 + col] = f2bf(acc0);
            if(r2+1 < nr) h1c[(base + r2 + 1)*16 + col] = f2bf(acc1);
        }
    }
}

// ================= scan: blockwise inclusive (1024 elems/block) =================
__global__ __launch_bounds__(256) void scanA_kernel(const int* __restrict__ deg,
                                                    int* __restrict__ incl,
                                                    int* __restrict__ bsum, int n3)
{
    __shared__ int sh[256];
    int t = threadIdx.x;
    long base = (long)blockIdx.x*1024 + t*4;
    int v0=0,v1=0,v2=0,v3=0;
    if(base   < n3) v0 = deg[base];
    if(base+1 < n3) v1 = deg[base+1];
    if(base+2 < n3) v2 = deg[base+2];
    if(base+3 < n3) v3 = deg[base+3];
    int tot = v0+v1+v2+v3;
    sh[t] = tot;
    __syncthreads();
    for(int ofs = 1; ofs < 256; ofs <<= 1){
        int add = (t >= ofs) ? sh[t-ofs] : 0;
        __syncthreads();
        sh[t] += add;
        __syncthreads();
    }
    int pre = sh[t] - tot;
    if(t == 255) bsum[blockIdx.x] = sh[255];
    int s0 = pre+v0, s1 = s0+v1, s2 = s1+v2, s3 = s2+v3;
    if(base   < n3) incl[base]   = s0;
    if(base+1 < n3) incl[base+1] = s1;
    if(base+2 < n3) incl[base+2] = s2;
    if(base+3 < n3) incl[base+3] = s3;
}

__global__ __launch_bounds__(512) void scanB_kernel(int* __restrict__ bsum, int nb)
{
    __shared__ int sh[512];
    int t = threadIdx.x;
    int v = (t < nb) ? bsum[t] : 0;
    sh[t] = v;
    __syncthreads();
    for(int ofs = 1; ofs < 512; ofs <<= 1){
        int add = (t >= ofs) ? sh[t-ofs] : 0;
        __syncthreads();
        sh[t] += add;
        __syncthreads();
    }
    if(t < nb) bsum[t] = sh[t] - v;   // exclusive
}

// ====== scanC + cursor init + (uniform-label_init) layer-1 output fused ======
__global__ __launch_bounds__(256) void scanC_kernel(
    const int* __restrict__ incl, const int* __restrict__ boff,
    int* __restrict__ rowptr, int* __restrict__ cursor, int n3,
    const float* __restrict__ label_init, const float* __restrict__ labels,
    const void* __restrict__ maskp, const unsigned* __restrict__ flags,
    unsigned short* __restrict__ hA, int n)
{
    int i = blockIdx.x*blockDim.x + threadIdx.x;
    if(i >= n3) return;
    int ex = (i == 0) ? 0 : (incl[i-1] + boff[(i-1) >> 10]);
    int en = incl[i] + boff[i >> 10];
    rowptr[i] = ex;
    cursor[i] = ex;
    if(i == n3-1) rowptr[n3] = en;
    unsigned fl = *flags;
    if(!(fl & 4u)){
        int g = i / n;
        int d = i - g*n;
        float mk = get_mask(maskp, fl, d);
        float v = (en > ex) ? label_init[0]*(1.0f - mk) : 0.0f;
        const float4* lb = (const float4*)(labels + (long)d*16);
        ushort4* op = (ushort4*)(hA + (long)i*16);
        #pragma unroll
        for(int q = 0; q < 4; q++){
            float4 l4 = lb[q];
            ushort4 o;
            o.x = f2bf(v + l4.x*mk);
            o.y = f2bf(v + l4.y*mk);
            o.z = f2bf(v + l4.z*mk);
            o.w = f2bf(v + l4.w*mk);
            op[q] = o;
        }
    }
}

// ====== FUSED scores + cursor-atomic scatter of 4B {e15:15|src:17} records ======
// 4-edge ILP: 8 independent 128B gathers hide the cursor RMW round trip
// (r12-proven structure, 159us, replay-safe). NT stores for the random 4B rec.
__global__ __launch_bounds__(256) void score_scatter_packed(
    const unsigned short* __restrict__ fph,
    const int* __restrict__ src0, const int* __restrict__ dst0,
    const int* __restrict__ src1, const int* __restrict__ dst1,
    const int* __restrict__ src2, const int* __restrict__ dst2,
    int* __restrict__ cursor, unsigned* __restrict__ rec, int n, int eg)
{
    long tid = (long)blockIdx.x*blockDim.x + threadIdx.x;
    long gid = tid >> 3;
    long tot = 3L*eg;
    long e0 = gid*4;
    if(e0 >= tot) return;
    int l = threadIdx.x & 7;
    const uint4* f4 = (const uint4*)fph;

    int sv[4], dv[4], gv[4];
    bool ok[4];
    #pragma unroll
    for(int q = 0; q < 4; q++){
        long e = e0 + q;
        ok[q] = (e < tot);
        long ee = ok[q] ? e : (tot - 1);
        int g = (int)(ee / eg);
        int i = (int)(ee - (long)g*eg);
        const int* sp = g==0 ? src0 : (g==1 ? src1 : src2);
        const int* dp = g==0 ? dst0 : (g==1 ? dst1 : dst2);
        sv[q] = sp[i];
        dv[q] = dp[i];
        gv[q] = g;
    }
    uint4 A[4], B[4];
    #pragma unroll
    for(int q = 0; q < 4; q++){
        A[q] = f4[(long)sv[q]*8 + l];
        B[q] = f4[(long)dv[q]*8 + l];
    }
    float p[4];
    #pragma unroll
    for(int q = 0; q < 4; q++){
        float v;
        v  = bl(A[q].x)*bl(B[q].x) + bh(A[q].x)*bh(B[q].x);
        v += bl(A[q].y)*bl(B[q].y) + bh(A[q].y)*bh(B[q].y);
        v += bl(A[q].z)*bl(B[q].z) + bh(A[q].z)*bh(B[q].z);
        v += bl(A[q].w)*bl(B[q].w) + bh(A[q].w)*bh(B[q].w);
        p[q] = v;
    }
    #pragma unroll
    for(int q = 0; q < 4; q++){
        p[q] += __shfl_xor(p[q], 1);
        p[q] += __shfl_xor(p[q], 2);
        p[q] += __shfl_xor(p[q], 4);
    }
    if(l == 0){
        int pos[4];
        #pragma unroll
        for(int q = 0; q < 4; q++){
            if(ok[q]) pos[q] = atomicAdd(&cursor[(long)gv[q]*n + dv[q]], 1);
        }
        #pragma unroll
        for(int q = 0; q < 4; q++){
            if(ok[q]){
                float s = fminf(fmaxf(p[q]*0.125f, -10.0f), 10.0f);  // /sqrt(64)
                unsigned u = __float_as_uint(__expf(s)) + 0x1000u;   // round bit13
                unsigned e15 = (u >> 13) - (112u << 10);
                unsigned pk = (e15 << 17) | (unsigned)sv[q];
                __builtin_nontemporal_store(pk, rec + pos[q]);
            }
        }
    }
}

// ====== per-row bf16 propagate body (4B rec, den inline), 4 classes per call ======
__device__ __forceinline__ void prop_row_bf16(
    const unsigned* __restrict__ rec, int beg, int end,
    const unsigned short* __restrict__ hg, int c4,
    float &a0, float &a1, float &a2, float &a3)
{
    float den = 0.f;
    a0 = a1 = a2 = a3 = 0.f;
    int j = beg;
    if((j & 1) && j < end){
        unsigned p = rec[j];
        float e = dec15(p >> 17);
        den += e;
        uint2 hv = *((const uint2*)(hg + (long)(p & 0x1FFFFu)*16 + c4));
        a0 += e*bl(hv.x); a1 += e*bh(hv.x); a2 += e*bl(hv.y); a3 += e*bh(hv.y);
        j++;
    }
    for(; j + 1 < end; j += 2){
        uint2 rr = *((const uint2*)(rec + j));   // 2 records, 8B
        float e0 = dec15(rr.x >> 17);
        float e1 = dec15(rr.y >> 17);
        den += e0 + e1;
        uint2 hv0 = *((const uint2*)(hg + (long)(rr.x & 0x1FFFFu)*16 + c4));
        uint2 hv1 = *((const uint2*)(hg + (long)(rr.y & 0x1FFFFu)*16 + c4));
        a0 += e0*bl(hv0.x) + e1*bl(hv1.x);
        a1 += e0*bh(hv0.x) + e1*bh(hv1.x);
        a2 += e0*bl(hv0.y) + e1*bl(hv1.y);
        a3 += e0*bh(hv0.y) + e1*bh(hv1.y);
    }
    if(j < end){
        unsigned p = rec[j];
        float e = dec15(p >> 17);
        den += e;
        uint2 hv = *((const uint2*)(hg + (long)(p & 0x1FFFFu)*16 + c4));
        a0 += e*bl(hv.x); a1 += e*bh(hv.x); a2 += e*bl(hv.y); a3 += e*bh(hv.y);
    }
    float inv = 1.0f/(den + 1e-16f);
    a0 *= inv; a1 *= inv; a2 *= inv; a3 *= inv;
}

// ====== layer-1 fallback (non-uniform label_init only): f32 gathers ======
__global__ __launch_bounds__(256) void prop1_fallback_kernel(
    const int* __restrict__ rowptr, const unsigned* __restrict__ rec,
    const float* __restrict__ h_in_f32, unsigned short* __restrict__ h_next,
    const float* __restrict__ labels, const void* __restrict__ maskp,
    const unsigned* __restrict__ flags, int n)
{
    unsigned fl = *flags;
    if(!(fl & 4u)) return;   // uniform case handled in scanC
    long tid = (long)blockIdx.x*blockDim.x + threadIdx.x;
    int row = (int)(tid >> 2);
    int c4 = (int)(tid & 3)*4;
    if(row >= 3*n) return;
    int g = row / n;
    int d = row - g*n;
    int beg = rowptr[row], end = rowptr[row+1];
    float a0=0.f, a1=0.f, a2=0.f, a3=0.f, den=0.f;
    for(int j = beg; j < end; j++){
        unsigned p = rec[j];
        float e = dec15(p >> 17);
        den += e;
        float4 hv = *((const float4*)(h_in_f32 + (long)(p & 0x1FFFFu)*16 + c4));
        a0 += e*hv.x; a1 += e*hv.y; a2 += e*hv.z; a3 += e*hv.w;
    }
    float inv = 1.0f/(den + 1e-16f);
    float mk = get_mask(maskp, fl, d);
    float im = (1.0f - mk)*inv;
    float4 lb = *((const float4*)(labels + (long)d*16 + c4));
    ushort4 o;
    o.x = f2bf(a0*im + lb.x*mk);
    o.y = f2bf(a1*im + lb.y*mk);
    o.z = f2bf(a2*im + lb.z*mk);
    o.w = f2bf(a3*im + lb.w*mk);
    *((ushort4*)(h_next + (long)row*16 + c4)) = o;
}

// ====== middle layer + NS aggregate fused by grid partition ======
__global__ __launch_bounds__(256) void prop_mid_ns_kernel(
    const int* __restrict__ rowptr, const unsigned* __restrict__ rec,
    const unsigned short* __restrict__ h_in, unsigned short* __restrict__ h_next,
    const float* __restrict__ labels, const void* __restrict__ maskp,
    const unsigned* __restrict__ flags, int n, int nbMid,
    const float* __restrict__ h0c, const unsigned short* __restrict__ h1c,
    const int* __restrict__ nei, float* __restrict__ out, int kk)
{
    int t = threadIdx.x;
    if(blockIdx.x < nbMid){
        long tid = (long)blockIdx.x*256 + t;
        int row = (int)(tid >> 2);
        int c4 = (int)(tid & 3)*4;
        if(row >= 3*n) return;
        int g = row / n;
        int d = row - g*n;
        float a0, a1, a2, a3;
        prop_row_bf16(rec, rowptr[row], rowptr[row+1], h_in + (long)g*n*16, c4,
                      a0, a1, a2, a3);
        unsigned fl = *flags;
        float mk = get_mask(maskp, fl, d);
        float im = 1.0f - mk;
        float4 lb = *((const float4*)(labels + (long)d*16 + c4));
        ushort4 o;
        o.x = f2bf(a0*im + lb.x*mk);
        o.y = f2bf(a1*im + lb.y*mk);
        o.z = f2bf(a2*im + lb.z*mk);
        o.w = f2bf(a3*im + lb.w*mk);
        *((ushort4*)(h_next + (long)row*16 + c4)) = o;
    } else {
        long tid = (long)(blockIdx.x - nbMid)*256 + t;
        int node = (int)(tid >> 2);
        int c4 = (int)(tid & 3)*4;
        if(node >= n) return;
        const int* nrow = nei + (long)node*kk;
        float s0=0.f, s1=0.f, s2=0.f, s3=0.f;
        for(int j = 0; j < kk; j++){
            int nb = nrow[j];
            uint2 hv = *((const uint2*)(h1c + (long)nb*16 + c4));
            s0 += bl(hv.x); s1 += bh(hv.x); s2 += bl(hv.y); s3 += bh(hv.y);
        }
        float invk = 1.0f/(float)kk;
        float4 h0 = *((const float4*)(h0c + (long)node*16 + c4));
        float4 o2;
        o2.x = h0.x + s0*invk; o2.y = h0.y + s1*invk;
        o2.z = h0.z + s2*invk; o2.w = h0.w + s3*invk;
        *((float4*)(out + (long)2*n*16 + (long)node*16 + c4)) = o2;
    }
}

// ====== FUSED layer-3 propagate (3 graphs) + attn mix + gate (ns read from out) ======
__global__ __launch_bounds__(256) void prop3_ns_kernel(
    const int* __restrict__ rowptr, const unsigned* __restrict__ rec,
    const unsigned short* __restrict__ h_in, const float* __restrict__ labels,
    const void* __restrict__ maskp, const unsigned* __restrict__ flags,
    const float* __restrict__ attn, const float* __restrict__ alpha,
    float* __restrict__ out, int n)
{
    long tid = (long)blockIdx.x*blockDim.x + threadIdx.x;
    int node = (int)(tid >> 2);
    int c4 = (int)(tid & 3)*4;
    if(node >= n) return;
    unsigned fl = *flags;
    float mk = get_mask(maskp, fl, node);
    float im = 1.0f - mk;
    float4 lb = *((const float4*)(labels + (long)node*16 + c4));

    float lp_[3][4];
    #pragma unroll
    for(int g = 0; g < 3; g++){
        int row = g*n + node;
        float a0, a1, a2, a3;
        prop_row_bf16(rec, rowptr[row], rowptr[row+1], h_in + (long)g*n*16, c4,
                      a0, a1, a2, a3);
        lp_[g][0] = a0*im + lb.x*mk;
        lp_[g][1] = a1*im + lb.y*mk;
        lp_[g][2] = a2*im + lb.z*mk;
        lp_[g][3] = a3*im + lb.w*mk;
    }
    float t0 = attn[node*3], t1 = attn[node*3+1], t2 = attn[node*3+2];
    float mx = fmaxf(t0, fmaxf(t1, t2));
    float e0 = __expf(t0-mx), e1 = __expf(t1-mx), e2 = __expf(t2-mx);
    float inv = 1.0f/(e0+e1+e2);
    e0 *= inv; e1 *= inv; e2 *= inv;
    float lp0 = e0*lp_[0][0] + e1*lp_[1][0] + e2*lp_[2][0];
    float lp1 = e0*lp_[0][1] + e1*lp_[1][1] + e2*lp_[2][1];
    float lp2 = e0*lp_[0][2] + e1*lp_[1][2] + e2*lp_[2][2];
    float lp3 = e0*lp_[0][3] + e1*lp_[1][3] + e2*lp_[2][3];

    long gs = (long)n*16;
    long idx = (long)node*16 + c4;
    float4 ns = *((const float4*)(out + 2*gs + idx));   // written by prop_mid_ns
    float al = alpha[node];
    float sg = 1.0f/(1.0f + __expf(-al));
    float isg = 1.0f - sg;
    float4 o0; o0.x = sg*lp0 + isg*ns.x; o0.y = sg*lp1 + isg*ns.y;
               o0.z = sg*lp2 + isg*ns.z; o0.w = sg*lp3 + isg*ns.w;
    float4 o1; o1.x = lp0; o1.y = lp1; o1.z = lp2; o1.w = lp3;
    *((float4*)(out + idx))      = o0;
    *((float4*)(out + gs + idx)) = o1;
}

// ================= launch =================
extern "C" void kernel_launch(void* const* d_in, const int* in_sizes, int n_in,
                              void* d_out, int out_size, void* d_ws, size_t ws_size,
                              hipStream_t stream)
{
    const float* feats0     = (const float*)d_in[0];
    const float* feats1     = (const float*)d_in[1];
    const float* W0         = (const float*)d_in[2];
    const float* b0         = (const float*)d_in[3];
    const float* W1         = (const float*)d_in[4];
    const float* b1         = (const float*)d_in[5];
    const float* Wp         = (const float*)d_in[6];
    const float* Wcls       = (const float*)d_in[7];
    const float* bcls       = (const float*)d_in[8];
    const float* alpha      = (const float*)d_in[9];
    const float* attn       = (const float*)d_in[10];
    const float* labels     = (const float*)d_in[11];
    const float* label_init = (const float*)d_in[12];
    const void*  maskp      = d_in[13];
    const int*   nei        = (const int*)d_in[14];
    const int*   src0       = (const int*)d_in[15];
    const int*   dst0       = (const int*)d_in[16];
    const int*   src1       = (const int*)d_in[17];
    const int*   dst1       = (const int*)d_in[18];
    const int*   src2       = (const int*)d_in[19];
    const int*   dst2       = (const int*)d_in[20];

    const int n  = in_sizes[9];          // N
    const int n1 = in_sizes[1] / 128;    // N1
    const int eg = in_sizes[15];         // E per graph
    const int kk = in_sizes[14] / n;     // K
    const int n3 = 3*n;

    // ---- workspace arena (~58 MB) ----
    char* ws = (char*)d_ws;
    size_t off = 0;
    auto alloc = [&](size_t bytes)->char*{
        char* p = ws + off; off += (bytes + 255) & ~(size_t)255; return p;
    };
    unsigned*       flags  = (unsigned*)      alloc(256);
    unsigned short* fph    = (unsigned short*)alloc((size_t)n*64*2);      // 12.8 MB
    float*          h0c    = (float*)         alloc((size_t)n*16*4);      // 6.4 MB
    unsigned short* h1c    = (unsigned short*)alloc((size_t)n1*16*2);     // 2.56 MB
    float*          W0c    = (float*)         alloc(2048*4);
    float*          W1c    = (float*)         alloc(2048*4);
    float*          b0c    = (float*)         alloc(64);
    float*          b1c    = (float*)         alloc(64);
    int*            deg    = (int*)           alloc((size_t)n3*4);        // aliases incl
    int*            cursor = (int*)           alloc((size_t)n3*4);
    int*            bsum   = (int*)           alloc(512*4);
    int*            rowptr = (int*)           alloc(((size_t)n3+1)*4);
    unsigned*       rec    = (unsigned*)      alloc((size_t)3*eg*4);      // 12 MB
    unsigned short* hA     = (unsigned short*)alloc((size_t)n3*16*2);     // 9.6 MB
    unsigned short* hB     = (unsigned short*)alloc((size_t)n3*16*2);     // 9.6 MB
    int* incl = deg;  // safe alias: scanA reads deg[i] before writing incl[i], per-thread

    // 1. init flags (deg zeroed inside prep)
    hipMemsetAsync(flags, 0, 4, stream);

    // 2. prep: small weights (block 0) + detection + deg zero (other blocks)
    long li_n = (long)n*16;
    {
        unsigned gsz = 1 + (unsigned)((li_n + 255)/256);
        prep_kernel<<<gsz, 256, 0, stream>>>(W0, b0, W1, b1, Wcls, bcls,
                                             W0c, W1c, b0c, b1c,
                                             (const unsigned char*)maskp, n,
                                             (const unsigned*)label_init, li_n, flags,
                                             deg, n3);
    }

    // 3. MEGA v4 (16 KB LDS): fire&forget count ∥ proj_fused0 ∥ proj16
    {
        long tot = 3L*eg;
        int nbCount = (int)((tot + 255)/256);
        int nbP0    = (n + 31)/32;
        int nbP16   = (n1 + 31)/32;
        mega_kernel<<<nbCount + nbP0 + nbP16, 256, 0, stream>>>(
            dst0, dst1, dst2, deg, n, eg, nbCount,
            feats0, Wp, W0c, b0c, fph, h0c, n, nbP0,
            feats1, W1c, b1c, h1c, n1);
    }

    // 4. CSR rowptr build + cursor init; scanC also emits layer-1 output (uniform case)
    int nb = (n3 + 1023)/1024;
    scanA_kernel<<<nb, 256, 0, stream>>>(deg, incl, bsum, n3);
    scanB_kernel<<<1, 512, 0, stream>>>(bsum, nb);
    scanC_kernel<<<(n3+255)/256, 256, 0, stream>>>(incl, bsum, rowptr, cursor, n3,
                                                   label_init, labels, maskp, flags,
                                                   hA, n);

    // 5. FUSED scores + cursor-atomic 4B record scatter (RMW hides under gathers)
    {
        long groups = (3L*eg + 3)/4;
        long tthreads = groups*8;
        score_scatter_packed<<<(unsigned)((tthreads+255)/256), 256, 0, stream>>>(
            fph, src0,dst0,src1,dst1,src2,dst2, cursor, rec, n, eg);
    }

    // 6. layer-1 fallback (no-op when uniform); layer-2 + NS aggregate (grid partition)
    prop1_fallback_kernel<<<(unsigned)(((long)n3*4+255)/256), 256, 0, stream>>>(
        rowptr, rec, label_init, hA, labels, maskp, flags, n);
    {
        int nbMid = (int)(((long)n3*4 + 255)/256);
        int nbNS  = (int)(((long)n*4 + 255)/256);
        prop_mid_ns_kernel<<<nbMid + nbNS, 256, 0, stream>>>(
            rowptr, rec, hA, hB, labels, maskp, flags, n, nbMid,
            h0c, h1c, nei, (float*)d_out, kk);
    }

    // 7. FUSED layer-3 + attention mix + gate (ns read back from out section 2)
    prop3_ns_kernel<<<(unsigned)(((long)n*4+255)/256), 256, 0, stream>>>(
        rowptr, rec, hB, labels, maskp, flags, attn, alpha, (float*)d_out, n);
}

// Round 23
// 440.776 us; speedup vs baseline: 1.0896x; 1.0896x over previous
//
#include <hip/hip_runtime.h>
#include <stdint.h>
#include <stddef.h>

// ================= helpers =================
__device__ __forceinline__ float bl(unsigned u){ return __uint_as_float(u << 16); }
__device__ __forceinline__ float bh(unsigned u){ return __uint_as_float(u & 0xffff0000u); }
__device__ __forceinline__ unsigned short f2bf(float f){
    unsigned u = __float_as_uint(f);
    unsigned r = (u + 0x7fffu + ((u >> 16) & 1u)) >> 16;
    return (unsigned short)r;
}
// 15-bit float (5 exp bias 15, 10 mant): exp(s) for s in [-10,10] fits exactly.
__device__ __forceinline__ float dec15(unsigned e15){
    return __uint_as_float((e15 + (112u << 10)) << 13);
}
__device__ __forceinline__ float get_mask(const void* p, unsigned flags, int i){
    if((flags & 1u) == 0) return ((const int*)p)[i] ? 1.0f : 0.0f;
    if(flags & 2u)        return ((const float*)p)[i];
    return ((const unsigned char*)p)[i] ? 1.0f : 0.0f;
}

// ====== PREP: block 0 = small weight products; blocks 1.. = detection + deg zero ======
__global__ __launch_bounds__(256) void prep_kernel(
    const float* __restrict__ W0, const float* __restrict__ b0,
    const float* __restrict__ W1, const float* __restrict__ b1,
    const float* __restrict__ Wcls, const float* __restrict__ bcls,
    float* __restrict__ W0c, float* __restrict__ W1c,
    float* __restrict__ b0c, float* __restrict__ b1c,
    const unsigned char* __restrict__ mp, int n,
    const unsigned* __restrict__ li, long li_n, unsigned* __restrict__ flags,
    int* __restrict__ deg, int n3)
{
    int t = threadIdx.x;
    if(blockIdx.x == 0){
        for(int i = t; i < 2048; i += 256){
            int d = i >> 4, c = i & 15;
            float s0 = 0.f, s1 = 0.f;
            for(int k = 0; k < 64; k++){
                float wc = Wcls[k*16 + c];
                s0 += W0[d*64 + k]*wc;
                s1 += W1[d*64 + k]*wc;
            }
            W0c[i] = s0; W1c[i] = s1;
        }
        if(t < 16){
            float s0 = 0.f, s1 = 0.f;
            for(int k = 0; k < 64; k++){
                float wc = Wcls[k*16 + t];
                s0 += b0[k]*wc; s1 += b1[k]*wc;
            }
            b0c[t] = s0 + bcls[t];
            b1c[t] = s1;
        }
    } else {
        long i = (long)(blockIdx.x - 1)*256 + t;
        if(i < n3) deg[i] = 0;
        unsigned f = 0;
        if(i < n){
            unsigned char b = mp[i];
            if((i & 3) && b) f |= 1u;
            if(b == 0x3Fu)   f |= 2u;
        }
        if(i < li_n){
            if(li[i] != li[0]) f |= 4u;
        }
        if(f) atomicOr(flags, f);
    }
}

// ====== MEGA: grid-partitioned {count_rank | proj_fused0 | proj16} ======
// Blocks [0,nbCount): count+rank (atomic-with-return stalls). Blocks after:
// projection streaming that overlaps under the count's latency window.
// LDS: 56KB union (proj_fused0 uses all; proj16 uses 40KB; count none).
__global__ __launch_bounds__(256) void mega_kernel(
    // count part
    const int* __restrict__ dst0, const int* __restrict__ dst1, const int* __restrict__ dst2,
    int* __restrict__ deg, int* __restrict__ rank, int n, int eg, int nbCount,
    // proj_fused0 part
    const float* __restrict__ X0, const float* __restrict__ Wp,
    const float* __restrict__ W0c, const float* __restrict__ b0c,
    unsigned short* __restrict__ fph, float* __restrict__ h0c, int rows0, int nbP0,
    // proj16 part
    const float* __restrict__ X1, const float* __restrict__ W1c,
    const float* __restrict__ b1c, unsigned short* __restrict__ h1c, int rows1)
{
    __shared__ __align__(16) float smem[14336];   // 56 KB
    int t = threadIdx.x;
    int b = blockIdx.x;
    if(b < nbCount){
        // ---- count + rank (replay-safe 1-edge/thread) ----
        long tid = (long)b*256 + t;
        if(tid < 3L*eg){
            int g = (int)(tid / eg);
            int e = (int)(tid - (long)g*eg);
            const int* dp = g==0 ? dst0 : (g==1 ? dst1 : dst2);
            int r = atomicAdd(&deg[(long)g*n + dp[e]], 1);
            __builtin_nontemporal_store(r, rank + tid);
        }
    } else if(b < nbCount + nbP0){
        // ---- proj_fused0: one 32-row tile ----
        float* Wl    = smem;           // 8192 floats (32 KB)
        float* Wcl   = smem + 8192;    // 2048 floats (8 KB)
        float* ftile = smem + 10240;   // 4096 floats (16 KB)
        for(int i = t; i < 2048; i += 256) ((float4*)Wl)[i]  = ((const float4*)Wp)[i];
        for(int i = t; i < 512;  i += 256) ((float4*)Wcl)[i] = ((const float4*)W0c)[i];
        int c4 = (t & 15)*4;
        int col16 = t & 15;
        int r2 = (t >> 4)*2;
        float bc = b0c[col16];
        long base = (long)(b - nbCount)*32;
        if(base < rows0){
            int nr = min(32, (int)(rows0 - base));
            __syncthreads();
            for(int i = t; i < nr*32; i += 256){
                int r = i >> 5, q = i & 31;
                ((float4*)ftile)[r*32 + q] = ((const float4*)X0)[(base + r)*32 + q];
            }
            __syncthreads();
            float a00=0,a01=0,a02=0,a03=0, a10=0,a11=0,a12=0,a13=0;
            float c0 = bc, c1 = bc;
            #pragma unroll 4
            for(int k = 0; k < 128; k++){
                float4 w = *((const float4*)(Wl + k*64 + c4));
                float wc = Wcl[k*16 + col16];
                float x0 = ftile[r2*128 + k];
                float x1 = ftile[(r2+1)*128 + k];
                a00 += x0*w.x; a01 += x0*w.y; a02 += x0*w.z; a03 += x0*w.w; c0 += x0*wc;
                a10 += x1*w.x; a11 += x1*w.y; a12 += x1*w.z; a13 += x1*w.w; c1 += x1*wc;
            }
            if(r2 < nr){
                ushort4 o; o.x=f2bf(a00); o.y=f2bf(a01); o.z=f2bf(a02); o.w=f2bf(a03);
                *((ushort4*)(fph + (base + r2)*64 + c4)) = o;
                h0c[(base + r2)*16 + col16] = c0;
            }
            if(r2 + 1 < nr){
                ushort4 o; o.x=f2bf(a10); o.y=f2bf(a11); o.z=f2bf(a12); o.w=f2bf(a13);
                *((ushort4*)(fph + (base + r2 + 1)*64 + c4)) = o;
                h0c[(base + r2 + 1)*16 + col16] = c1;
            }
        }
    } else {
        // ---- proj16: one 64-row tile ----
        float* Wcl   = smem;           // 2048 floats (8 KB)
        float* ftile = smem + 2048;    // 8192 floats (32 KB)
        for(int i = t; i < 512; i += 256) ((float4*)Wcl)[i] = ((const float4*)W1c)[i];
        int col = t & 15;
        int r4 = (t >> 4)*4;
        float bc = b1c[col];
        long base = (long)(b - nbCount - nbP0)*64;
        if(base < rows1){
            int nr = min(64, (int)(rows1 - base));
            __syncthreads();
            for(int i = t; i < nr*32; i += 256){
                int r = i >> 5, q = i & 31;
                ((float4*)ftile)[r*32 + q] = ((const float4*)X1)[(base + r)*32 + q];
            }
            __syncthreads();
            float acc0 = bc, acc1 = bc, acc2 = bc, acc3 = bc;
            #pragma unroll 4
            for(int k = 0; k < 128; k++){
                float wc = Wcl[k*16 + col];
                acc0 += ftile[(r4+0)*128 + k]*wc;
                acc1 += ftile[(r4+1)*128 + k]*wc;
                acc2 += ftile[(r4+2)*128 + k]*wc;
                acc3 += ftile[(r4+3)*128 + k]*wc;
            }
            if(r4+0 < nr) h1c[(base + r4 + 0)*16 + col] = f2bf(acc0);
            if(r4+1 < nr) h1c[(base + r4 + 1)*16 + col] = f2bf(acc1);
            if(r4+2 < nr) h1c[(base + r4 + 2)*16 + col] = f2bf(acc2);
            if(r4+3 < nr) h1c[(base + r4 + 3)*16 + col] = f2bf(acc3);
        }
    }
}

// ================= scan: blockwise inclusive (1024 elems/block) =================
__global__ __launch_bounds__(256) void scanA_kernel(const int* __restrict__ deg,
                                                    int* __restrict__ incl,
                                                    int* __restrict__ bsum, int n3)
{
    __shared__ int sh[256];
    int t = threadIdx.x;
    long base = (long)blockIdx.x*1024 + t*4;
    int v0=0,v1=0,v2=0,v3=0;
    if(base   < n3) v0 = deg[base];
    if(base+1 < n3) v1 = deg[base+1];
    if(base+2 < n3) v2 = deg[base+2];
    if(base+3 < n3) v3 = deg[base+3];
    int tot = v0+v1+v2+v3;
    sh[t] = tot;
    __syncthreads();
    for(int ofs = 1; ofs < 256; ofs <<= 1){
        int add = (t >= ofs) ? sh[t-ofs] : 0;
        __syncthreads();
        sh[t] += add;
        __syncthreads();
    }
    int pre = sh[t] - tot;
    if(t == 255) bsum[blockIdx.x] = sh[255];
    int s0 = pre+v0, s1 = s0+v1, s2 = s1+v2, s3 = s2+v3;
    if(base   < n3) incl[base]   = s0;
    if(base+1 < n3) incl[base+1] = s1;
    if(base+2 < n3) incl[base+2] = s2;
    if(base+3 < n3) incl[base+3] = s3;
}

__global__ __launch_bounds__(512) void scanB_kernel(int* __restrict__ bsum, int nb)
{
    __shared__ int sh[512];
    int t = threadIdx.x;
    int v = (t < nb) ? bsum[t] : 0;
    sh[t] = v;
    __syncthreads();
    for(int ofs = 1; ofs < 512; ofs <<= 1){
        int add = (t >= ofs) ? sh[t-ofs] : 0;
        __syncthreads();
        sh[t] += add;
        __syncthreads();
    }
    if(t < nb) bsum[t] = sh[t] - v;   // exclusive
}

// ====== scanC + (uniform-label_init) layer-1 output fused ======
__global__ __launch_bounds__(256) void scanC_kernel(
    const int* __restrict__ incl, const int* __restrict__ boff,
    int* __restrict__ rowptr, int n3,
    const float* __restrict__ label_init, const float* __restrict__ labels,
    const void* __restrict__ maskp, const unsigned* __restrict__ flags,
    unsigned short* __restrict__ hA, int n)
{
    int i = blockIdx.x*blockDim.x + threadIdx.x;
    if(i >= n3) return;
    int ex = (i == 0) ? 0 : (incl[i-1] + boff[(i-1) >> 10]);
    int en = incl[i] + boff[i >> 10];
    rowptr[i] = ex;
    if(i == n3-1) rowptr[n3] = en;
    unsigned fl = *flags;
    if(!(fl & 4u)){
        int g = i / n;
        int d = i - g*n;
        float mk = get_mask(maskp, fl, d);
        float v = (en > ex) ? label_init[0]*(1.0f - mk) : 0.0f;
        const float4* lb = (const float4*)(labels + (long)d*16);
        ushort4* op = (ushort4*)(hA + (long)i*16);
        #pragma unroll
        for(int q = 0; q < 4; q++){
            float4 l4 = lb[q];
            ushort4 o;
            o.x = f2bf(v + l4.x*mk);
            o.y = f2bf(v + l4.y*mk);
            o.z = f2bf(v + l4.z*mk);
            o.w = f2bf(v + l4.w*mk);
            op[q] = o;
        }
    }
}

// ====== FUSED scores + scatter of 4B packed {e15:15|src:17} records, 4-edge ILP ======
// pos = rowptr[row] + rank[e]  (NO atomics). e=exp(s) as 15-bit float. NT stores.
__global__ __launch_bounds__(256) void score_scatter_packed(
    const unsigned short* __restrict__ fph,
    const int* __restrict__ src0, const int* __restrict__ dst0,
    const int* __restrict__ src1, const int* __restrict__ dst1,
    const int* __restrict__ src2, const int* __restrict__ dst2,
    const int* __restrict__ rowptr, const int* __restrict__ rank,
    unsigned* __restrict__ rec, int n, int eg)
{
    long tid = (long)blockIdx.x*blockDim.x + threadIdx.x;
    long gid = tid >> 3;
    long tot = 3L*eg;
    long e0 = gid*4;
    if(e0 >= tot) return;
    int l = threadIdx.x & 7;
    const uint4* f4 = (const uint4*)fph;

    int sv[4], dv[4], gv[4], rk[4];
    bool ok[4];
    #pragma unroll
    for(int q = 0; q < 4; q++){
        long e = e0 + q;
        ok[q] = (e < tot);
        long ee = ok[q] ? e : (tot - 1);
        int g = (int)(ee / eg);
        int i = (int)(ee - (long)g*eg);
        const int* sp = g==0 ? src0 : (g==1 ? src1 : src2);
        const int* dp = g==0 ? dst0 : (g==1 ? dst1 : dst2);
        sv[q] = sp[i];
        dv[q] = dp[i];
        gv[q] = g;
        rk[q] = rank[ee];
    }
    uint4 A[4], B[4];
    #pragma unroll
    for(int q = 0; q < 4; q++){
        A[q] = f4[(long)sv[q]*8 + l];
        B[q] = f4[(long)dv[q]*8 + l];
    }
    float p[4];
    #pragma unroll
    for(int q = 0; q < 4; q++){
        float v;
        v  = bl(A[q].x)*bl(B[q].x) + bh(A[q].x)*bh(B[q].x);
        v += bl(A[q].y)*bl(B[q].y) + bh(A[q].y)*bh(B[q].y);
        v += bl(A[q].z)*bl(B[q].z) + bh(A[q].z)*bh(B[q].z);
        v += bl(A[q].w)*bl(B[q].w) + bh(A[q].w)*bh(B[q].w);
        p[q] = v;
    }
    #pragma unroll
    for(int q = 0; q < 4; q++){
        p[q] += __shfl_xor(p[q], 1);
        p[q] += __shfl_xor(p[q], 2);
        p[q] += __shfl_xor(p[q], 4);
    }
    if(l == 0){
        #pragma unroll
        for(int q = 0; q < 4; q++){
            if(ok[q]){
                int pos = rowptr[(long)gv[q]*n + dv[q]] + rk[q];
                float s = fminf(fmaxf(p[q]*0.125f, -10.0f), 10.0f);  // /sqrt(64)
                unsigned u = __float_as_uint(__expf(s)) + 0x1000u;   // round bit13
                unsigned e15 = (u >> 13) - (112u << 10);
                unsigned pk = (e15 << 17) | (unsigned)sv[q];
                __builtin_nontemporal_store(pk, rec + pos);
            }
        }
    }
}

// ====== per-row bf16 propagate body (4B rec, den inline), 4 classes per call ======
__device__ __forceinline__ void prop_row_bf16(
    const unsigned* __restrict__ rec, int beg, int end,
    const unsigned short* __restrict__ hg, int c4,
    float &a0, float &a1, float &a2, float &a3)
{
    float den = 0.f;
    a0 = a1 = a2 = a3 = 0.f;
    int j = beg;
    if((j & 1) && j < end){
        unsigned p = rec[j];
        float e = dec15(p >> 17);
        den += e;
        uint2 hv = *((const uint2*)(hg + (long)(p & 0x1FFFFu)*16 + c4));
        a0 += e*bl(hv.x); a1 += e*bh(hv.x); a2 += e*bl(hv.y); a3 += e*bh(hv.y);
        j++;
    }
    for(; j + 1 < end; j += 2){
        uint2 rr = *((const uint2*)(rec + j));   // 2 records, 8B
        float e0 = dec15(rr.x >> 17);
        float e1 = dec15(rr.y >> 17);
        den += e0 + e1;
        uint2 hv0 = *((const uint2*)(hg + (long)(rr.x & 0x1FFFFu)*16 + c4));
        uint2 hv1 = *((const uint2*)(hg + (long)(rr.y & 0x1FFFFu)*16 + c4));
        a0 += e0*bl(hv0.x) + e1*bl(hv1.x);
        a1 += e0*bh(hv0.x) + e1*bh(hv1.x);
        a2 += e0*bl(hv0.y) + e1*bl(hv1.y);
        a3 += e0*bh(hv0.y) + e1*bh(hv1.y);
    }
    if(j < end){
        unsigned p = rec[j];
        float e = dec15(p >> 17);
        den += e;
        uint2 hv = *((const uint2*)(hg + (long)(p & 0x1FFFFu)*16 + c4));
        a0 += e*bl(hv.x); a1 += e*bh(hv.x); a2 += e*bl(hv.y); a3 += e*bh(hv.y);
    }
    float inv = 1.0f/(den + 1e-16f);
    a0 *= inv; a1 *= inv; a2 *= inv; a3 *= inv;
}

// ====== layer-1 fallback (non-uniform label_init only): f32 gathers ======
__global__ __launch_bounds__(256) void prop1_fallback_kernel(
    const int* __restrict__ rowptr, const unsigned* __restrict__ rec,
    const float* __restrict__ h_in_f32, unsigned short* __restrict__ h_next,
    const float* __restrict__ labels, const void* __restrict__ maskp,
    const unsigned* __restrict__ flags, int n)
{
    unsigned fl = *flags;
    if(!(fl & 4u)) return;   // uniform case handled in scanC
    long tid = (long)blockIdx.x*blockDim.x + threadIdx.x;
    int row = (int)(tid >> 2);
    int c4 = (int)(tid & 3)*4;
    if(row >= 3*n) return;
    int g = row / n;
    int d = row - g*n;
    int beg = rowptr[row], end = rowptr[row+1];
    float a0=0.f, a1=0.f, a2=0.f, a3=0.f, den=0.f;
    for(int j = beg; j < end; j++){
        unsigned p = rec[j];
        float e = dec15(p >> 17);
        den += e;
        float4 hv = *((const float4*)(h_in_f32 + (long)(p & 0x1FFFFu)*16 + c4));
        a0 += e*hv.x; a1 += e*hv.y; a2 += e*hv.z; a3 += e*hv.w;
    }
    float inv = 1.0f/(den + 1e-16f);
    float mk = get_mask(maskp, fl, d);
    float im = (1.0f - mk)*inv;
    float4 lb = *((const float4*)(labels + (long)d*16 + c4));
    ushort4 o;
    o.x = f2bf(a0*im + lb.x*mk);
    o.y = f2bf(a1*im + lb.y*mk);
    o.z = f2bf(a2*im + lb.z*mk);
    o.w = f2bf(a3*im + lb.w*mk);
    *((ushort4*)(h_next + (long)row*16 + c4)) = o;
}

// ====== middle layer + NS aggregate fused by grid partition ======
__global__ __launch_bounds__(256) void prop_mid_ns_kernel(
    const int* __restrict__ rowptr, const unsigned* __restrict__ rec,
    const unsigned short* __restrict__ h_in, unsigned short* __restrict__ h_next,
    const float* __restrict__ labels, const void* __restrict__ maskp,
    const unsigned* __restrict__ flags, int n, int nbMid,
    const float* __restrict__ h0c, const unsigned short* __restrict__ h1c,
    const int* __restrict__ nei, float* __restrict__ out, int kk)
{
    int t = threadIdx.x;
    if(blockIdx.x < nbMid){
        long tid = (long)blockIdx.x*256 + t;
        int row = (int)(tid >> 2);
        int c4 = (int)(tid & 3)*4;
        if(row >= 3*n) return;
        int g = row / n;
        int d = row - g*n;
        float a0, a1, a2, a3;
        prop_row_bf16(rec, rowptr[row], rowptr[row+1], h_in + (long)g*n*16, c4,
                      a0, a1, a2, a3);
        unsigned fl = *flags;
        float mk = get_mask(maskp, fl, d);
        float im = 1.0f - mk;
        float4 lb = *((const float4*)(labels + (long)d*16 + c4));
        ushort4 o;
        o.x = f2bf(a0*im + lb.x*mk);
        o.y = f2bf(a1*im + lb.y*mk);
        o.z = f2bf(a2*im + lb.z*mk);
        o.w = f2bf(a3*im + lb.w*mk);
        *((ushort4*)(h_next + (long)row*16 + c4)) = o;
    } else {
        long tid = (long)(blockIdx.x - nbMid)*256 + t;
        int node = (int)(tid >> 2);
        int c4 = (int)(tid & 3)*4;
        if(node >= n) return;
        const int* nrow = nei + (long)node*kk;
        float s0=0.f, s1=0.f, s2=0.f, s3=0.f;
        for(int j = 0; j < kk; j++){
            int nb = nrow[j];
            uint2 hv = *((const uint2*)(h1c + (long)nb*16 + c4));
            s0 += bl(hv.x); s1 += bh(hv.x); s2 += bl(hv.y); s3 += bh(hv.y);
        }
        float invk = 1.0f/(float)kk;
        float4 h0 = *((const float4*)(h0c + (long)node*16 + c4));
        float4 o2;
        o2.x = h0.x + s0*invk; o2.y = h0.y + s1*invk;
        o2.z = h0.z + s2*invk; o2.w = h0.w + s3*invk;
        *((float4*)(out + (long)2*n*16 + (long)node*16 + c4)) = o2;
    }
}

// ====== FUSED layer-3 propagate (3 graphs) + attn mix + gate (ns read from out) ======
__global__ __launch_bounds__(256) void prop3_ns_kernel(
    const int* __restrict__ rowptr, const unsigned* __restrict__ rec,
    const unsigned short* __restrict__ h_in, const float* __restrict__ labels,
    const void* __restrict__ maskp, const unsigned* __restrict__ flags,
    const float* __restrict__ attn, const float* __restrict__ alpha,
    float* __restrict__ out, int n)
{
    long tid = (long)blockIdx.x*blockDim.x + threadIdx.x;
    int node = (int)(tid >> 2);
    int c4 = (int)(tid & 3)*4;
    if(node >= n) return;
    unsigned fl = *flags;
    float mk = get_mask(maskp, fl, node);
    float im = 1.0f - mk;
    float4 lb = *((const float4*)(labels + (long)node*16 + c4));

    float lp_[3][4];
    #pragma unroll
    for(int g = 0; g < 3; g++){
        int row = g*n + node;
        float a0, a1, a2, a3;
        prop_row_bf16(rec, rowptr[row], rowptr[row+1], h_in + (long)g*n*16, c4,
                      a0, a1, a2, a3);
        lp_[g][0] = a0*im + lb.x*mk;
        lp_[g][1] = a1*im + lb.y*mk;
        lp_[g][2] = a2*im + lb.z*mk;
        lp_[g][3] = a3*im + lb.w*mk;
    }
    float t0 = attn[node*3], t1 = attn[node*3+1], t2 = attn[node*3+2];
    float mx = fmaxf(t0, fmaxf(t1, t2));
    float e0 = __expf(t0-mx), e1 = __expf(t1-mx), e2 = __expf(t2-mx);
    float inv = 1.0f/(e0+e1+e2);
    e0 *= inv; e1 *= inv; e2 *= inv;
    float lp0 = e0*lp_[0][0] + e1*lp_[1][0] + e2*lp_[2][0];
    float lp1 = e0*lp_[0][1] + e1*lp_[1][1] + e2*lp_[2][1];
    float lp2 = e0*lp_[0][2] + e1*lp_[1][2] + e2*lp_[2][2];
    float lp3 = e0*lp_[0][3] + e1*lp_[1][3] + e2*lp_[2][3];

    long gs = (long)n*16;
    long idx = (long)node*16 + c4;
    float4 ns = *((const float4*)(out + 2*gs + idx));   // written by prop_mid_ns
    float al = alpha[node];
    float sg = 1.0f/(1.0f + __expf(-al));
    float isg = 1.0f - sg;
    float4 o0; o0.x = sg*lp0 + isg*ns.x; o0.y = sg*lp1 + isg*ns.y;
               o0.z = sg*lp2 + isg*ns.z; o0.w = sg*lp3 + isg*ns.w;
    float4 o1; o1.x = lp0; o1.y = lp1; o1.z = lp2; o1.w = lp3;
    *((float4*)(out + idx))      = o0;
    *((float4*)(out + gs + idx)) = o1;
}

// ================= launch =================
extern "C" void kernel_launch(void* const* d_in, const int* in_sizes, int n_in,
                              void* d_out, int out_size, void* d_ws, size_t ws_size,
                              hipStream_t stream)
{
    const float* feats0     = (const float*)d_in[0];
    const float* feats1     = (const float*)d_in[1];
    const float* W0         = (const float*)d_in[2];
    const float* b0         = (const float*)d_in[3];
    const float* W1         = (const float*)d_in[4];
    const float* b1         = (const float*)d_in[5];
    const float* Wp         = (const float*)d_in[6];
    const float* Wcls       = (const float*)d_in[7];
    const float* bcls       = (const float*)d_in[8];
    const float* alpha      = (const float*)d_in[9];
    const float* attn       = (const float*)d_in[10];
    const float* labels     = (const float*)d_in[11];
    const float* label_init = (const float*)d_in[12];
    const void*  maskp      = d_in[13];
    const int*   nei        = (const int*)d_in[14];
    const int*   src0       = (const int*)d_in[15];
    const int*   dst0       = (const int*)d_in[16];
    const int*   src1       = (const int*)d_in[17];
    const int*   dst1       = (const int*)d_in[18];
    const int*   src2       = (const int*)d_in[19];
    const int*   dst2       = (const int*)d_in[20];

    const int n  = in_sizes[9];          // N
    const int n1 = in_sizes[1] / 128;    // N1
    const int eg = in_sizes[15];         // E per graph
    const int kk = in_sizes[14] / n;     // K
    const int n3 = 3*n;

    // ---- workspace arena (~70 MB) ----
    char* ws = (char*)d_ws;
    size_t off = 0;
    auto alloc = [&](size_t bytes)->char*{
        char* p = ws + off; off += (bytes + 255) & ~(size_t)255; return p;
    };
    unsigned*       flags  = (unsigned*)      alloc(256);
    unsigned short* fph    = (unsigned short*)alloc((size_t)n*64*2);      // 12.8 MB
    float*          h0c    = (float*)         alloc((size_t)n*16*4);      // 6.4 MB
    unsigned short* h1c    = (unsigned short*)alloc((size_t)n1*16*2);     // 2.56 MB
    float*          W0c    = (float*)         alloc(2048*4);
    float*          W1c    = (float*)         alloc(2048*4);
    float*          b0c    = (float*)         alloc(64);
    float*          b1c    = (float*)         alloc(64);
    int*            deg    = (int*)           alloc((size_t)n3*4);        // aliases incl
    int*            bsum   = (int*)           alloc(512*4);
    int*            rowptr = (int*)           alloc(((size_t)n3+1)*4);
    int*            rank   = (int*)           alloc((size_t)3*eg*4);      // 12 MB
    unsigned*       rec    = (unsigned*)      alloc((size_t)3*eg*4);      // 12 MB
    unsigned short* hA     = (unsigned short*)alloc((size_t)n3*16*2);     // 9.6 MB
    unsigned short* hB     = (unsigned short*)alloc((size_t)n3*16*2);     // 9.6 MB
    int* incl = deg;  // safe alias: scanA reads deg[i] before writing incl[i], per-thread

    // 1. init flags (deg zeroed inside prep)
    hipMemsetAsync(flags, 0, 4, stream);

    // 2. prep: small weights (block 0) + detection + deg zero (other blocks)
    long li_n = (long)n*16;
    {
        unsigned gsz = 1 + (unsigned)((li_n + 255)/256);
        prep_kernel<<<gsz, 256, 0, stream>>>(W0, b0, W1, b1, Wcls, bcls,
                                             W0c, W1c, b0c, b1c,
                                             (const unsigned char*)maskp, n,
                                             (const unsigned*)label_init, li_n, flags,
                                             deg, n3);
    }

    // 3. MEGA: count+rank (blocks first) + proj_fused0 + proj16, grid-partitioned
    {
        long tot = 3L*eg;
        int nbCount = (int)((tot + 255)/256);
        int nbP0    = (n + 31)/32;
        int nbP16   = (n1 + 63)/64;
        mega_kernel<<<nbCount + nbP0 + nbP16, 256, 0, stream>>>(
            dst0, dst1, dst2, deg, rank, n, eg, nbCount,
            feats0, Wp, W0c, b0c, fph, h0c, n, nbP0,
            feats1, W1c, b1c, h1c, n1);
    }

    // 4. CSR rowptr build; scanC also emits layer-1 output (uniform case)
    int nb = (n3 + 1023)/1024;
    scanA_kernel<<<nb, 256, 0, stream>>>(deg, incl, bsum, n3);
    scanB_kernel<<<1, 512, 0, stream>>>(bsum, nb);
    scanC_kernel<<<(n3+255)/256, 256, 0, stream>>>(incl, bsum, rowptr, n3,
                                                   label_init, labels, maskp, flags,
                                                   hA, n);

    // 5. FUSED scores + 4B record scatter — NO atomics (pos = rowptr + rank)
    {
        long groups = (3L*eg + 3)/4;
        long tthreads = groups*8;
        score_scatter_packed<<<(unsigned)((tthreads+255)/256), 256, 0, stream>>>(
            fph, src0,dst0,src1,dst1,src2,dst2, rowptr, rank, rec, n, eg);
    }

    // 6. layer-1 fallback (no-op when uniform); layer-2 + NS aggregate (grid partition)
    prop1_fallback_kernel<<<(unsigned)(((long)n3*4+255)/256), 256, 0, stream>>>(
        rowptr, rec, label_init, hA, labels, maskp, flags, n);
    {
        int nbMid = (int)(((long)n3*4 + 255)/256);
        int nbNS  = (int)(((long)n*4 + 255)/256);
        prop_mid_ns_kernel<<<nbMid + nbNS, 256, 0, stream>>>(
            rowptr, rec, hA, hB, labels, maskp, flags, n, nbMid,
            h0c, h1c, nei, (float*)d_out, kk);
    }

    // 7. FUSED layer-3 + attention mix + gate (ns read back from out section 2)
    prop3_ns_kernel<<<(unsigned)(((long)n*4+255)/256), 256, 0, stream>>>(
        rowptr, rec, hB, labels, maskp, flags, attn, alpha, (float*)d_out, n);
}